// Round 6
// baseline (3756.894 us; speedup 1.0000x reference)
//
#include <hip/hip_runtime.h>
#include <hip/hip_fp16.h>
#include <math.h>

#define DFEAT 256
#define KITER 10
#define ALPHA 0.1f
#define BETA 0.9f
#define SCAN_CHUNK 2048   // per 256-thread block, 8 elems/thread
#define BUCKET_SHIFT 15   // 4 column buckets of 32768 rows (2MB of 64B slice-lines)

#define WSCALE 268435456.0   // 2^28 fixed-point for weight sums (34-bit field)
#define WSUM_MASK ((1ULL << 34) - 1)

typedef float f32x4 __attribute__((ext_vector_type(4)));
typedef unsigned u32;
typedef unsigned long long u64;

// ---------------- setup kernels ----------------

// ONE u64 atomic per edge:
//   [wsum:34b @0][c0:7b @34][c1:7b @41][c2:7b @48][c3:7b @55]
// Returned old value gives this edge's rank within its (row, col-bucket).
__global__ void pass1_kernel(const int* __restrict__ row, const int* __restrict__ col,
                             const float* __restrict__ w,
                             u64* __restrict__ pk, u32* __restrict__ rankA, int E) {
    int e = blockIdx.x * 256 + threadIdx.x;
    if (e < E) {
        int r = row[e];
        u32 b = ((u32)col[e]) >> BUCKET_SHIFT;          // 0..3
        u64 add = (u64)((double)w[e] * WSCALE) | (1ULL << (34 + 7 * b));
        u64 old = atomicAdd(&pk[r], add);
        rankA[e] = (u32)((old >> (34 + 7 * b)) & 0x7F);
    }
}

// dinv[i] = rsqrt(deg_i + 1), deg from packed wsum bits.
__global__ void dinv_kernel(const u64* __restrict__ pk, float* __restrict__ dinv, int n) {
    int i = blockIdx.x * 256 + threadIdx.x;
    if (i < n) {
        float deg = (float)((double)(pk[i] & WSUM_MASK) * (1.0 / WSCALE));
        dinv[i] = rsqrtf(deg + 1.0f);
    }
}

// --- hierarchical scan of per-row totals (sum of 4 bucket counts) ---

__global__ __launch_bounds__(256) void scan1_kernel(const u64* __restrict__ pk,
                                                    int* __restrict__ row_ptr,
                                                    int* __restrict__ partial, int n) {
    __shared__ int wsum[4];
    int b = blockIdx.x;
    int base = b * SCAN_CHUNK;
    int tid = threadIdx.x;
    int lane = tid & 63, wv = tid >> 6;

    int v[8];
    int s = 0;
    #pragma unroll
    for (int j = 0; j < 8; ++j) {
        int i = base + tid * 8 + j;
        int cnt = 0;
        if (i < n) {
            u64 q = pk[i];
            cnt = (int)(((q >> 34) & 0x7F) + ((q >> 41) & 0x7F) +
                        ((q >> 48) & 0x7F) + ((q >> 55) & 0x7F));
        }
        v[j] = cnt;
        s += cnt;
    }
    int incl = s;
    #pragma unroll
    for (int off = 1; off < 64; off <<= 1) {
        int t = __shfl_up(incl, off, 64);
        if (lane >= off) incl += t;
    }
    if (lane == 63) wsum[wv] = incl;
    __syncthreads();
    int woff = 0;
    for (int w = 0; w < wv; ++w) woff += wsum[w];
    int run = woff + incl - s;
    #pragma unroll
    for (int j = 0; j < 8; ++j) {
        int i = base + tid * 8 + j;
        if (i < n) row_ptr[i] = run;
        run += v[j];
    }
    if (tid == 255) partial[b] = run;
}

__global__ void scan2_kernel(int* __restrict__ partial, int nb) {
    __shared__ int tmp[1024];
    int tid = threadIdx.x;
    int v = (tid < nb) ? partial[tid] : 0;
    tmp[tid] = v;
    __syncthreads();
    for (int off = 1; off < 1024; off <<= 1) {
        int t = (tid >= off) ? tmp[tid - off] : 0;
        __syncthreads();
        tmp[tid] += t;
        __syncthreads();
    }
    if (tid < nb) partial[tid] = tmp[tid] - v;
}

__global__ void scan3_kernel(int* __restrict__ row_ptr,
                             const int* __restrict__ partial, int n, int E) {
    int i = blockIdx.x * 256 + threadIdx.x;
    if (i < n) {
        row_ptr[i] += partial[i / SCAN_CHUNK];
    } else if (i == n) {
        row_ptr[n] = E;
    }
}

// Atomic-free scatter, bucket-ordered within row.
// cwp packs (w fp16 with lsb dropped, bits[17..31]) | (col, bits[0..16]).
__global__ void scatter_kernel(const int* __restrict__ row, const int* __restrict__ col,
                               const float* __restrict__ w, const u32* __restrict__ rankA,
                               const u64* __restrict__ pk, const int* __restrict__ row_ptr,
                               u32* __restrict__ cwp, int E) {
    int e = blockIdx.x * 256 + threadIdx.x;
    if (e < E) {
        int r = row[e];
        u32 c = (u32)col[e];
        u32 b = c >> BUCKET_SHIFT;
        u64 v = pk[r];
        u32 c0 = (u32)((v >> 34) & 0x7F);
        u32 c1 = (u32)((v >> 41) & 0x7F);
        u32 c2 = (u32)((v >> 48) & 0x7F);
        u32 off = (b > 0 ? c0 : 0) + (b > 1 ? c1 : 0) + (b > 2 ? c2 : 0);
        u32 pos = (u32)row_ptr[r] + off + rankA[e];
        u32 wb = (u32)__half_as_ushort(__float2half_rn(w[e])) & 0xFFFEu;
        cwp[pos] = (wb << 16) | c;   // wb<<16 has bit16==0, col uses bits[0..16]
    }
}

// x' = dinv[row] * x, stored fp16 row-major (g-space initial state AND alpha term).
__global__ void xprime_kernel(const float* __restrict__ x, const float* __restrict__ dinv,
                              __half* __restrict__ dst, size_t n4) {
    size_t i = (size_t)blockIdx.x * 256 + threadIdx.x;
    if (i < n4) {
        float4 v = ((const float4*)x)[i];
        float dr = dinv[i >> 6];   // 64 float4's per row of 256 feats
        __half2 h0 = __floats2half2_rn(dr * v.x, dr * v.y);
        __half2 h1 = __floats2half2_rn(dr * v.z, dr * v.w);
        float2 o;
        o.x = *reinterpret_cast<float*>(&h0);
        o.y = *reinterpret_cast<float*>(&h1);
        ((float2*)dst)[i] = o;
    }
}

// ---------------- feature-sliced SpMM iteration ----------------
// g'[r] = BETA*dr^2*( sum_e w_e*g[c_e] + g[r] ) + ALPHA*x'[r]; final /(dr*GAMMA).
// Slice s = blockIdx&7 (-> XCD via round-robin): feats [s*32, s*32+32) = 64B.
// Per-XCD L2 only sees its own slice (6.4MB) in 2MB column-bucket windows.
// Wave = one (row, slice): 16 groups x 4 lanes; group g handles edges e0+g (stride 16),
// 4 lanes x 16B = the 64B slice per gather. Butterfly shfl_xor reduces 16 partials.
template<int FINAL>
__global__ __launch_bounds__(256) void spmm_slice_kernel(
        const __half* __restrict__ in, const __half* __restrict__ xh,
        float* __restrict__ outf, __half* __restrict__ outh,
        const int* __restrict__ row_ptr, const u32* __restrict__ cwp,
        const float* __restrict__ dinv, int n, float inv_gamma) {
    int wave = threadIdx.x >> 6;
    int lane = threadIdx.x & 63;
    u32 s = (u32)blockIdx.x & 7u;
    int r = (blockIdx.x >> 3) * 4 + wave;
    if (r >= n) return;

    int start = row_ptr[r];
    int end   = row_ptr[r + 1];
    int g   = lane >> 2;
    int sub = lane & 3;

    // this lane's 8 channels: feats [s*32 + sub*8, +8)
    float a00 = 0.f, a01 = 0.f, a10 = 0.f, a11 = 0.f;
    float a20 = 0.f, a21 = 0.f, a30 = 0.f, a31 = 0.f;

    const __half* sbase = in + (s << 5) + (sub << 3);   // + col*256 per gather
    for (int e = start + g; e < end; e += 16) {
        u32 p = __builtin_nontemporal_load(cwp + e);
        u32 c = p & 0x1FFFFu;
        float wf = __half2float(__ushort_as_half((unsigned short)((p >> 16) & 0xFFFEu)));
        f32x4 v = *(const f32x4*)(sbase + ((size_t)c << 8));
        __half2* hv = (__half2*)&v;
        float2 f0 = __half22float2(hv[0]);
        float2 f1 = __half22float2(hv[1]);
        float2 f2 = __half22float2(hv[2]);
        float2 f3 = __half22float2(hv[3]);
        a00 += wf * f0.x; a01 += wf * f0.y;
        a10 += wf * f1.x; a11 += wf * f1.y;
        a20 += wf * f2.x; a21 += wf * f2.y;
        a30 += wf * f3.x; a31 += wf * f3.y;
    }

    // reduce across the 16 groups (lanes with equal sub)
    #pragma unroll
    for (int m = 4; m < 64; m <<= 1) {
        a00 += __shfl_xor(a00, m, 64);
        a01 += __shfl_xor(a01, m, 64);
        a10 += __shfl_xor(a10, m, 64);
        a11 += __shfl_xor(a11, m, 64);
        a20 += __shfl_xor(a20, m, 64);
        a21 += __shfl_xor(a21, m, 64);
        a30 += __shfl_xor(a30, m, 64);
        a31 += __shfl_xor(a31, m, 64);
    }

    if (g == 0) {
        size_t off = ((size_t)r << 8) + (s << 5) + (sub << 3);
        float dr = dinv[r];
        float c1v = BETA * dr * dr;

        // self term (weight exactly 1)
        f32x4 sv = *(const f32x4*)(in + off);
        __half2* sh = (__half2*)&sv;
        float2 s0 = __half22float2(sh[0]);
        float2 s1 = __half22float2(sh[1]);
        float2 s2 = __half22float2(sh[2]);
        float2 s3 = __half22float2(sh[3]);

        f32x4 xv = __builtin_nontemporal_load((const f32x4*)(xh + off));
        __half2* xp = (__half2*)&xv;
        float2 x0 = __half22float2(xp[0]);
        float2 x1 = __half22float2(xp[1]);
        float2 x2 = __half22float2(xp[2]);
        float2 x3 = __half22float2(xp[3]);

        float o00 = c1v * (a00 + s0.x) + ALPHA * x0.x;
        float o01 = c1v * (a01 + s0.y) + ALPHA * x0.y;
        float o10 = c1v * (a10 + s1.x) + ALPHA * x1.x;
        float o11 = c1v * (a11 + s1.y) + ALPHA * x1.y;
        float o20 = c1v * (a20 + s2.x) + ALPHA * x2.x;
        float o21 = c1v * (a21 + s2.y) + ALPHA * x2.y;
        float o30 = c1v * (a30 + s3.x) + ALPHA * x3.x;
        float o31 = c1v * (a31 + s3.y) + ALPHA * x3.y;

        if (FINAL) {
            float up = inv_gamma / dr;   // back to h-space
            float* op = outf + off;
            f32x4 w0 = { o00 * up, o01 * up, o10 * up, o11 * up };
            f32x4 w1 = { o20 * up, o21 * up, o30 * up, o31 * up };
            __builtin_nontemporal_store(w0, (f32x4*)op);
            __builtin_nontemporal_store(w1, (f32x4*)(op + 4));
        } else {
            f32x4 ov;
            __half2* oh = (__half2*)&ov;
            oh[0] = __floats2half2_rn(o00, o01);
            oh[1] = __floats2half2_rn(o10, o11);
            oh[2] = __floats2half2_rn(o20, o21);
            oh[3] = __floats2half2_rn(o30, o31);
            __builtin_nontemporal_store(ov, (f32x4*)(outh + off));
        }
    }
}

// ---------------- launch ----------------

extern "C" void kernel_launch(void* const* d_in, const int* in_sizes, int n_in,
                              void* d_out, int out_size, void* d_ws, size_t ws_size,
                              hipStream_t stream) {
    const float* x  = (const float*)d_in[0];
    const float* ew = (const float*)d_in[1];
    const int*   ei = (const int*)d_in[2];
    int n = in_sizes[0] / DFEAT;
    int E = in_sizes[1];
    const int* row = ei;
    const int* col = ei + E;
    float* out = (float*)d_out;

    char* ws = (char*)d_ws;
    auto alloc = [&](size_t bytes) {
        char* p = ws;
        ws += (bytes + 255) & ~(size_t)255;
        return p;
    };
    u64*    pk      = (u64*)  alloc((size_t)n * 8);
    u32*    rankA   = (u32*)  alloc((size_t)E * 4);
    int*    row_ptr = (int*)  alloc((size_t)(n + 1) * 4);
    int*    partial = (int*)  alloc((size_t)1024 * 4);
    float*  dinv    = (float*)alloc((size_t)n * 4);
    u32*    cwp     = (u32*)  alloc((size_t)E * 4);
    __half* xh      = (__half*)alloc((size_t)n * DFEAT * 2);
    __half* H0      = (__half*)alloc((size_t)n * DFEAT * 2);
    __half* H1      = (__half*)d_out;   // alias: dead before final fp32 write

    hipMemsetAsync(pk, 0, (size_t)n * 8, stream);

    pass1_kernel<<<(E + 255) / 256, 256, 0, stream>>>(row, col, ew, pk, rankA, E);
    dinv_kernel<<<(n + 255) / 256, 256, 0, stream>>>(pk, dinv, n);

    int nb = (n + SCAN_CHUNK - 1) / SCAN_CHUNK;
    scan1_kernel<<<nb, 256, 0, stream>>>(pk, row_ptr, partial, n);
    scan2_kernel<<<1, 1024, 0, stream>>>(partial, nb);
    scan3_kernel<<<(n + 256) / 256, 256, 0, stream>>>(row_ptr, partial, n, E);

    scatter_kernel<<<(E + 255) / 256, 256, 0, stream>>>(row, col, ew, rankA, pk,
                                                        row_ptr, cwp, E);

    size_t n4 = (size_t)n * DFEAT / 4;
    xprime_kernel<<<(int)((n4 + 255) / 256), 256, 0, stream>>>(x, dinv, xh, n4);

    // GAMMA == 1.0 exactly for these constants, but compute anyway.
    double gamma = pow((double)BETA, KITER);
    for (int i = 0; i < KITER; ++i) gamma += (double)ALPHA * pow((double)BETA, i);
    float inv_gamma = (float)(1.0 / gamma);

    int grid = 8 * ((n + 3) / 4);   // (slice = blockIdx&7, row-group = blockIdx>>3)
    const __half* cur = xh;
    __half* bufs[2] = { H0, H1 };   // k even -> H0, k odd -> H1(d_out alias)
    for (int k = 0; k < KITER; ++k) {
        if (k < KITER - 1) {
            __half* o = bufs[k & 1];
            spmm_slice_kernel<0><<<grid, 256, 0, stream>>>(cur, xh, nullptr, o,
                                                           row_ptr, cwp, dinv, n, 1.0f);
            cur = o;
        } else {
            // k=9 reads H0 (k=8 wrote H0), writes fp32 to d_out (H1 dead)
            spmm_slice_kernel<1><<<grid, 256, 0, stream>>>(cur, xh, out, nullptr,
                                                           row_ptr, cwp, dinv, n, inv_gamma);
        }
    }
}

// Round 7
// 1431.812 us; speedup vs baseline: 2.6239x; 2.6239x over previous
//
#include <hip/hip_runtime.h>
#include <hip/hip_fp16.h>
#include <math.h>

#define DFEAT 256
#define KITER 10
#define ALPHA 0.1f
#define BETA 0.9f
#define SCAN_CHUNK 2048   // per 256-thread block, 8 elems/thread

#define WSCALE 268435456.0   // 2^28 fixed-point for edge weights
#define CNT_SHIFT 40

// ---------------- setup kernels ----------------

// One exact u64 atomic per edge: high bits count, low bits fixed-point weight sum.
// Returned old value yields this edge's rank within its row (old >> 40).
__global__ void edge_pass1_kernel(const int* __restrict__ row,
                                  const float* __restrict__ w,
                                  unsigned long long* __restrict__ pk,
                                  int* __restrict__ rank, int E) {
    int e = blockIdx.x * 256 + threadIdx.x;
    if (e < E) {
        int r = row[e];
        unsigned long long add = (1ULL << CNT_SHIFT) |
            (unsigned long long)((double)w[e] * WSCALE);
        unsigned long long old = atomicAdd(&pk[r], add);
        rank[e] = (int)(old >> CNT_SHIFT);
    }
}

// dinv[i] = rsqrt(deg_i + 1), deg from packed low bits.
__global__ void dinv_kernel(const unsigned long long* __restrict__ pk,
                            float* __restrict__ dinv, int n) {
    int i = blockIdx.x * 256 + threadIdx.x;
    if (i < n) {
        unsigned long long v = pk[i];
        float deg = (float)((double)(v & ((1ULL << CNT_SHIFT) - 1)) * (1.0 / WSCALE));
        dinv[i] = rsqrtf(deg + 1.0f);
    }
}

// --- hierarchical scan of counts (extracted from pk) -> row_ptr ---

__global__ __launch_bounds__(256) void scan1_kernel(const unsigned long long* __restrict__ pk,
                                                    int* __restrict__ row_ptr,
                                                    int* __restrict__ partial, int n) {
    __shared__ int wsum[4];
    int b = blockIdx.x;
    int base = b * SCAN_CHUNK;
    int tid = threadIdx.x;
    int lane = tid & 63, wv = tid >> 6;

    int v[8];
    int s = 0;
    #pragma unroll
    for (int j = 0; j < 8; ++j) {
        int i = base + tid * 8 + j;
        v[j] = (i < n) ? (int)(pk[i] >> CNT_SHIFT) : 0;
        s += v[j];
    }
    int incl = s;
    #pragma unroll
    for (int off = 1; off < 64; off <<= 1) {
        int t = __shfl_up(incl, off, 64);
        if (lane >= off) incl += t;
    }
    if (lane == 63) wsum[wv] = incl;
    __syncthreads();
    int woff = 0;
    for (int w = 0; w < wv; ++w) woff += wsum[w];
    int run = woff + incl - s;
    #pragma unroll
    for (int j = 0; j < 8; ++j) {
        int i = base + tid * 8 + j;
        if (i < n) row_ptr[i] = run;
        run += v[j];
    }
    if (tid == 255) partial[b] = run;
}

__global__ void scan2_kernel(int* __restrict__ partial, int nb) {
    __shared__ int tmp[1024];
    int tid = threadIdx.x;
    int v = (tid < nb) ? partial[tid] : 0;
    tmp[tid] = v;
    __syncthreads();
    for (int off = 1; off < 1024; off <<= 1) {
        int t = (tid >= off) ? tmp[tid - off] : 0;
        __syncthreads();
        tmp[tid] += t;
        __syncthreads();
    }
    if (tid < nb) partial[tid] = tmp[tid] - v;
}

__global__ void scan3_kernel(int* __restrict__ row_ptr,
                             const int* __restrict__ partial, int n, int E) {
    int i = blockIdx.x * 256 + threadIdx.x;
    if (i < n) {
        row_ptr[i] += partial[i / SCAN_CHUNK];
    } else if (i == n) {
        row_ptr[n] = E;
    }
}

// Atomic-free scatter: pos = row_ptr[r] + rank[e]; store RAW weight (g-space).
__global__ void scatter_kernel(const int* __restrict__ row, const int* __restrict__ col,
                               const float* __restrict__ w, const int* __restrict__ rank,
                               const int* __restrict__ row_ptr,
                               int2* __restrict__ cw, int E) {
    int e = blockIdx.x * 256 + threadIdx.x;
    if (e < E) {
        int r = row[e];
        int pos = row_ptr[r] + rank[e];
        cw[pos] = make_int2(col[e], __float_as_int(w[e]));
    }
}

// x' = dinv[row] * x, stored fp16 (g-space initial state AND the alpha term).
__global__ void xprime_kernel(const float* __restrict__ x, const float* __restrict__ dinv,
                              __half* __restrict__ dst, size_t n4) {
    size_t i = (size_t)blockIdx.x * 256 + threadIdx.x;
    if (i < n4) {
        float4 v = ((const float4*)x)[i];
        float dr = dinv[i >> 6];   // 64 float4's per row of 256 feats
        __half2 h0 = __floats2half2_rn(dr * v.x, dr * v.y);
        __half2 h1 = __floats2half2_rn(dr * v.z, dr * v.w);
        float2 o;
        o.x = *reinterpret_cast<float*>(&h0);
        o.y = *reinterpret_cast<float*>(&h1);
        ((float2*)dst)[i] = o;
    }
}

// ---------------- main SpMM iteration (g-space, fp16 state, fp32 accum) ----
// g'[r] = BETA*dr^2*( sum_e w_e*g[c_e] + g[r] ) + ALPHA*x'[r]
// final: out[r] = g'[r] / (dr * GAMMA)
// One wave per row; lane owns 4 feats (8B fp16 per lane).
// FETCH=433MB/iter == compulsory floor (354 unique-row + 64 streaming, R6 analysis);
// fabric rate ~4.1 TB/s is the structural ceiling for random 512B gathers.
#define ACC(g, wbits) { float wv = __int_as_float(wbits); \
    __half2 h0_ = *reinterpret_cast<__half2*>(&g.x); \
    __half2 h1_ = *reinterpret_cast<__half2*>(&g.y); \
    float2 u0_ = __half22float2(h0_); float2 u1_ = __half22float2(h1_); \
    a0 += wv * u0_.x; a1 += wv * u0_.y; a2 += wv * u1_.x; a3 += wv * u1_.y; }

template<int FINAL>
__global__ __launch_bounds__(256) void spmm_h_kernel(
        const __half* __restrict__ in, const __half* __restrict__ xh,
        float* __restrict__ outf, __half* __restrict__ outh,
        const int* __restrict__ row_ptr, const int2* __restrict__ cw,
        const float* __restrict__ dinv,
        int n, float inv_gamma) {
    int wave = threadIdx.x >> 6;
    int lane = threadIdx.x & 63;
    int r = blockIdx.x * 4 + wave;
    if (r >= n) return;

    int start = row_ptr[r];
    int end   = row_ptr[r + 1];
    float dr  = dinv[r];
    float c1  = BETA * dr * dr;

    const float2* inf2 = (const float2*)in;
    unsigned rbase = ((unsigned)r << 6) | (unsigned)lane;   // 64 float2 per row

    float2 xraw = ((const float2*)xh)[rbase];

    // self term, weight exactly 1
    float2 sraw = inf2[rbase];
    __half2 s0 = *reinterpret_cast<__half2*>(&sraw.x);
    __half2 s1 = *reinterpret_cast<__half2*>(&sraw.y);
    float2 sf0 = __half22float2(s0), sf1 = __half22float2(s1);
    float a0 = sf0.x, a1 = sf0.y, a2 = sf1.x, a3 = sf1.y;

    int e = start;
    for (; e + 8 <= end; e += 8) {
        int2 p0 = cw[e];
        int2 p1 = cw[e + 1];
        int2 p2 = cw[e + 2];
        int2 p3 = cw[e + 3];
        int2 p4 = cw[e + 4];
        int2 p5 = cw[e + 5];
        int2 p6 = cw[e + 6];
        int2 p7 = cw[e + 7];
        float2 g0 = inf2[((unsigned)p0.x << 6) | (unsigned)lane];
        float2 g1 = inf2[((unsigned)p1.x << 6) | (unsigned)lane];
        float2 g2 = inf2[((unsigned)p2.x << 6) | (unsigned)lane];
        float2 g3 = inf2[((unsigned)p3.x << 6) | (unsigned)lane];
        float2 g4 = inf2[((unsigned)p4.x << 6) | (unsigned)lane];
        float2 g5 = inf2[((unsigned)p5.x << 6) | (unsigned)lane];
        float2 g6 = inf2[((unsigned)p6.x << 6) | (unsigned)lane];
        float2 g7 = inf2[((unsigned)p7.x << 6) | (unsigned)lane];
        ACC(g0, p0.y);
        ACC(g1, p1.y);
        ACC(g2, p2.y);
        ACC(g3, p3.y);
        ACC(g4, p4.y);
        ACC(g5, p5.y);
        ACC(g6, p6.y);
        ACC(g7, p7.y);
    }
    for (; e + 4 <= end; e += 4) {
        int2 p0 = cw[e];
        int2 p1 = cw[e + 1];
        int2 p2 = cw[e + 2];
        int2 p3 = cw[e + 3];
        float2 g0 = inf2[((unsigned)p0.x << 6) | (unsigned)lane];
        float2 g1 = inf2[((unsigned)p1.x << 6) | (unsigned)lane];
        float2 g2 = inf2[((unsigned)p2.x << 6) | (unsigned)lane];
        float2 g3 = inf2[((unsigned)p3.x << 6) | (unsigned)lane];
        ACC(g0, p0.y);
        ACC(g1, p1.y);
        ACC(g2, p2.y);
        ACC(g3, p3.y);
    }
    for (; e < end; ++e) {
        int2 p = cw[e];
        float2 g = inf2[((unsigned)p.x << 6) | (unsigned)lane];
        ACC(g, p.y);
    }

    __half2 x0 = *reinterpret_cast<__half2*>(&xraw.x);
    __half2 x1 = *reinterpret_cast<__half2*>(&xraw.y);
    float2 xf0 = __half22float2(x0), xf1 = __half22float2(x1);
    float o0 = c1 * a0 + ALPHA * xf0.x;
    float o1 = c1 * a1 + ALPHA * xf0.y;
    float o2 = c1 * a2 + ALPHA * xf1.x;
    float o3 = c1 * a3 + ALPHA * xf1.y;

    if (FINAL) {
        float up = inv_gamma / dr;   // back to h-space
        ((float4*)(outf + (size_t)r * DFEAT))[lane] =
            make_float4(o0 * up, o1 * up, o2 * up, o3 * up);
    } else {
        __half2 h0 = __floats2half2_rn(o0, o1);
        __half2 h1 = __floats2half2_rn(o2, o3);
        float2 o;
        o.x = *reinterpret_cast<float*>(&h0);
        o.y = *reinterpret_cast<float*>(&h1);
        ((float2*)outh)[rbase] = o;
    }
}

// ---------------- launch ----------------

extern "C" void kernel_launch(void* const* d_in, const int* in_sizes, int n_in,
                              void* d_out, int out_size, void* d_ws, size_t ws_size,
                              hipStream_t stream) {
    const float* x  = (const float*)d_in[0];
    const float* ew = (const float*)d_in[1];
    const int*   ei = (const int*)d_in[2];
    int n = in_sizes[0] / DFEAT;
    int E = in_sizes[1];
    const int* row = ei;
    const int* col = ei + E;
    float* out = (float*)d_out;

    char* ws = (char*)d_ws;
    auto alloc = [&](size_t bytes) {
        char* p = ws;
        ws += (bytes + 255) & ~(size_t)255;
        return p;
    };
    unsigned long long* pk = (unsigned long long*)alloc((size_t)n * 8);
    int*    rank    = (int*)  alloc((size_t)E * 4);
    int*    row_ptr = (int*)  alloc((size_t)(n + 1) * 4);
    int*    partial = (int*)  alloc((size_t)1024 * 4);
    float*  dinv    = (float*)alloc((size_t)n * 4);
    int2*   cw      = (int2*) alloc((size_t)E * 8);
    __half* xh      = (__half*)alloc((size_t)n * DFEAT * 2);
    __half* H0      = (__half*)alloc((size_t)n * DFEAT * 2);
    __half* H1      = (__half*)d_out;   // alias: dead before final fp32 write

    hipMemsetAsync(pk, 0, (size_t)n * 8, stream);

    edge_pass1_kernel<<<(E + 255) / 256, 256, 0, stream>>>(row, ew, pk, rank, E);
    dinv_kernel<<<(n + 255) / 256, 256, 0, stream>>>(pk, dinv, n);

    int nb = (n + SCAN_CHUNK - 1) / SCAN_CHUNK;
    scan1_kernel<<<nb, 256, 0, stream>>>(pk, row_ptr, partial, n);
    scan2_kernel<<<1, 1024, 0, stream>>>(partial, nb);
    scan3_kernel<<<(n + 256) / 256, 256, 0, stream>>>(row_ptr, partial, n, E);

    scatter_kernel<<<(E + 255) / 256, 256, 0, stream>>>(row, col, ew, rank, row_ptr, cw, E);

    size_t n4 = (size_t)n * DFEAT / 4;
    xprime_kernel<<<(int)((n4 + 255) / 256), 256, 0, stream>>>(x, dinv, xh, n4);

    // GAMMA == 1.0 exactly for these constants, but compute anyway.
    double gamma = pow((double)BETA, KITER);
    for (int i = 0; i < KITER; ++i) gamma += (double)ALPHA * pow((double)BETA, i);
    float inv_gamma = (float)(1.0 / gamma);

    int grid = (n + 3) / 4;
    const __half* cur = xh;
    __half* bufs[2] = { H0, H1 };   // k even -> H0, k odd -> H1(d_out alias)
    for (int k = 0; k < KITER; ++k) {
        if (k < KITER - 1) {
            __half* o = bufs[k & 1];
            spmm_h_kernel<0><<<grid, 256, 0, stream>>>(cur, xh, nullptr, o,
                                                       row_ptr, cw, dinv, n, 1.0f);
            cur = o;
        } else {
            spmm_h_kernel<1><<<grid, 256, 0, stream>>>(cur, xh, out, nullptr,
                                                       row_ptr, cw, dinv, n, inv_gamma);
        }
    }
}